// Round 6
// baseline (918.805 us; speedup 1.0000x reference)
//
#include <hip/hip_runtime.h>
#include <hip/hip_bf16.h>

#define D 128
#define NP 8          // src-range sub-buckets per dst (aggregate pass loop)
#define KB 512        // coarse dst-range buckets
#define CAP 8192      // staging capacity per bucket (mean ~3125, stat. safe)
#define KPB_MAX 1600  // LDS fine-key array bound (dpb*NP = 196*8 = 1568)

typedef __attribute__((ext_vector_type(8))) __bf16 bf16x8;
typedef __attribute__((ext_vector_type(4))) float f32x4;
typedef __attribute__((ext_vector_type(4))) short s16x4;
typedef __attribute__((ext_vector_type(8))) short s16x8;

static __device__ __forceinline__ short f2bf(float f) {
    union { float f; unsigned u; } in; in.f = f;
    unsigned u = in.u;
    u += 0x7fffu + ((u >> 16) & 1u);   // round-to-nearest-even
    return (short)(u >> 16);
}

// ---- phase 1: coarse-bucket edges by dst range; sequential writes per bucket ----
// pack: fineKey(11b: d_local*8+srcHi) << 17 | src(17b)   [N=100000 < 2^17]
__global__ void k_bucket(const int* __restrict__ src, const int* __restrict__ dst,
                         int* __restrict__ bcnt, int* __restrict__ staging,
                         int E, int dpb, int spp) {
    int i = blockIdx.x * 256 + threadIdx.x;
    if (i >= E) return;
    int d = dst[i], s = src[i];
    int b = d / dpb;
    int dl = d - b * dpb;
    int sh = s / spp; if (sh > NP - 1) sh = NP - 1;
    int key = dl * NP + sh;
    int slot = atomicAdd(&bcnt[b], 1);
    if (slot < CAP) staging[(size_t)b * CAP + slot] = (key << 17) | s;
}

// ---- exclusive scan of 512 bucket counts + sentinel ----
__global__ void k_bscan(const int* __restrict__ bcnt, int* __restrict__ bbase,
                        int* __restrict__ row_ptr, int E, int nkeys) {
    __shared__ int sm[KB];
    int t = threadIdx.x;
    int v = bcnt[t];
    sm[t] = v;
    __syncthreads();
    for (int off = 1; off < KB; off <<= 1) {
        int x = (t >= off) ? sm[t - off] : 0;
        __syncthreads();
        sm[t] += x;
        __syncthreads();
    }
    bbase[t] = sm[t] - v;
    if (t == 0) row_ptr[nkeys] = E;
}

// ---- phase 2: per-bucket fine CSR build, all in LDS (no global atomics) ----
__global__ __launch_bounds__(256) void k_build(
    const int* __restrict__ staging, const int* __restrict__ bcnt,
    const int* __restrict__ bbase, int* __restrict__ row_ptr,
    int* __restrict__ csr_src, float* __restrict__ dinv, int N, int dpb)
{
    const int b = blockIdx.x;
    const int tid = threadIdx.x;
    const int kpb = dpb * NP;                 // 1568
    int nb = bcnt[b]; if (nb > CAP) nb = CAP;
    const int base = bbase[b];
    __shared__ int cnt[KPB_MAX];
    __shared__ int chunkbuf[256];
    __shared__ int carry;

    for (int k = tid; k < kpb; k += 256) cnt[k] = 0;
    if (tid == 0) carry = 0;
    __syncthreads();

    const int* sb = staging + (size_t)b * CAP;
    for (int t = tid; t < nb; t += 256)
        atomicAdd(&cnt[sb[t] >> 17], 1);
    __syncthreads();

    // in-place exclusive scan of cnt[0..kpb)
    const int nchunk = (kpb + 255) / 256;
    for (int c = 0; c < nchunk; c++) {
        int idx = c * 256 + tid;
        int v = (idx < kpb) ? cnt[idx] : 0;
        chunkbuf[tid] = v;
        __syncthreads();
        for (int off = 1; off < 256; off <<= 1) {
            int x = (tid >= off) ? chunkbuf[tid - off] : 0;
            __syncthreads();
            chunkbuf[tid] += x;
            __syncthreads();
        }
        int excl = chunkbuf[tid] - v + carry;   // reads old carry
        if (idx < kpb) cnt[idx] = excl;
        __syncthreads();
        if (tid == 255) carry += chunkbuf[255];
        __syncthreads();
    }

    // row_ptr (coalesced, contiguous global keys) + dinv for this dst range
    for (int k = tid; k < kpb; k += 256)
        row_ptr[(size_t)b * kpb + k] = base + cnt[k];
    for (int dl = tid; dl < dpb; dl += 256) {
        int d = b * dpb + dl;
        if (d < N) {
            int hi = (dl == dpb - 1) ? nb : cnt[(dl + 1) * NP];
            int deg = hi - cnt[dl * NP];
            dinv[d] = rsqrtf((float)deg + 1.0f);
        }
    }
    __syncthreads();

    // scatter into this bucket's contiguous csr region (LDS cursors)
    for (int t = tid; t < nb; t += 256) {
        int w = sb[t];
        int slot = base + atomicAdd(&cnt[w >> 17], 1);
        csr_src[slot] = w & 0x1FFFF;
    }
}

// ---- batch is SORTED: graph segment boundaries via binary search (no atomics) ----
__global__ void k_gseg(const int* __restrict__ batch, int* __restrict__ gstart,
                       int N, int B) {
    int g = blockIdx.x * blockDim.x + threadIdx.x;
    if (g > B) return;
    int lo = 0, hi = N;
    while (lo < hi) {                    // lower_bound: first i with batch[i] >= g
        int mid = (lo + hi) >> 1;
        if (batch[mid] < g) lo = mid + 1; else hi = mid;
    }
    gstart[g] = lo;
}

__global__ void k_gcnt_seg(const int* __restrict__ gstart, int* __restrict__ gcnt, int B) {
    int g = blockIdx.x * blockDim.x + threadIdx.x;
    if (g < B) gcnt[g] = gstart[g + 1] - gstart[g];
}

// ---- x' = dinv[i] * x  -> bf16 (pre-scaled feature rows) ----
__global__ void k_cvt_x(const float* __restrict__ x, const float* __restrict__ dinv,
                        short* __restrict__ xb, int total4) {
    int i = blockIdx.x * blockDim.x + threadIdx.x;
    if (i < total4) {
        float d = dinv[i >> 5];              // D/4 = 32 float4 per row
        float4 v = ((const float4*)x)[i];
        s16x4 o;
        o.x = f2bf(v.x * d); o.y = f2bf(v.y * d);
        o.z = f2bf(v.z * d); o.w = f2bf(v.w * d);
        ((s16x4*)xb)[i] = o;
    }
}

// ---- conv_w: fp32 [L][k][n] -> bf16 transposed [L][n][k] ----
__global__ void k_cvt_w(const float* __restrict__ W, short* __restrict__ Wt, int total) {
    int i = blockIdx.x * blockDim.x + threadIdx.x;
    if (i < total) {
        int l = i >> 14;
        int rem = i & 16383;
        int n = rem >> 7;
        int k = rem & 127;
        Wt[i] = f2bf(W[(l << 14) + (k << 7) + n]);
    }
}

// ---- pull-aggregation, src-range pass loop for L2 locality ----
// One 16-lane group owns one node (full 128-col row, 8 bf16/lane).
// Pass p gathers only rows in src-range p (~3.2 MB -> replicated in XCD L2s).
__global__ __launch_bounds__(256) void k_aggregate(
    const short* __restrict__ hb, const int* __restrict__ row_ptr,
    const int* __restrict__ csr_src, const float* __restrict__ dinv,
    short* __restrict__ g, int N)
{
    const int wave = threadIdx.x >> 6;
    const int lane = threadIdx.x & 63;
    const int group = lane >> 4;
    const int off = (lane & 15) * 8;
    const int i = blockIdx.x * 16 + wave * 4 + group;
    if (i >= N) return;   // no barriers below: early-out is safe

    float acc[8];
    {   // self-loop term
        bf16x8 v = *(const bf16x8*)(hb + (size_t)i * D + off);
        #pragma unroll
        for (int k = 0; k < 8; k++) acc[k] = (float)v[k];
    }

    const int kb = i * NP;
    int s = row_ptr[kb];
    #pragma unroll 1
    for (int p = 0; p < NP; p++) {
        int e = row_ptr[kb + p + 1];
        for (int t = s; t < e; t += 4) {   // 4-deep chained loads
            int i0 = csr_src[t];
            int i1 = (t + 1 < e) ? csr_src[t + 1] : -1;
            int i2 = (t + 2 < e) ? csr_src[t + 2] : -1;
            int i3 = (t + 3 < e) ? csr_src[t + 3] : -1;
            bf16x8 v0 = *(const bf16x8*)(hb + (size_t)i0 * D + off);
            bf16x8 v1, v2, v3;
            if (i1 >= 0) v1 = *(const bf16x8*)(hb + (size_t)i1 * D + off);
            if (i2 >= 0) v2 = *(const bf16x8*)(hb + (size_t)i2 * D + off);
            if (i3 >= 0) v3 = *(const bf16x8*)(hb + (size_t)i3 * D + off);
            #pragma unroll
            for (int k = 0; k < 8; k++) acc[k] += (float)v0[k];
            if (i1 >= 0) {
                #pragma unroll
                for (int k = 0; k < 8; k++) acc[k] += (float)v1[k];
            }
            if (i2 >= 0) {
                #pragma unroll
                for (int k = 0; k < 8; k++) acc[k] += (float)v2[k];
            }
            if (i3 >= 0) {
                #pragma unroll
                for (int k = 0; k < 8; k++) acc[k] += (float)v3[k];
            }
        }
        s = e;
    }

    const float di = dinv[i];
    s16x8 o;
    #pragma unroll
    for (int k = 0; k < 8; k++) o[k] = f2bf(acc[k] * di);
    *(s16x8*)(g + (size_t)i * D + off) = o;
}

// ---- bf16 MFMA GEMM: C = A[N x 128] * W, fused epilogue.
// mode 0: hb_out[r] = bf16( relu(C + b) * dinv[r] )   (pre-scaled next-layer rows)
// mode 1: hrelu[r]  = fp32 relu(C + b)                (pooling input)
__global__ __launch_bounds__(256) void k_gemm(const short* __restrict__ A,
                                              const short* __restrict__ Wt,
                                              const float* __restrict__ bias,
                                              const float* __restrict__ dinv,
                                              short* __restrict__ hb_out,
                                              float* __restrict__ hrelu,
                                              int N, int mode) {
    const int wave = threadIdx.x >> 6;
    const int lane = threadIdx.x & 63;
    const int m_base = blockIdx.x * 128 + wave * 32;
    const int lr = lane & 15;
    const int lq = lane >> 4;

    bf16x8 afrag[2][4];
    #pragma unroll
    for (int rt = 0; rt < 2; rt++) {
        int m = m_base + rt * 16 + lr;
        if (m >= N) m = N - 1;
        const short* ap = A + (size_t)m * D + lq * 8;
        #pragma unroll
        for (int kt = 0; kt < 4; kt++)
            afrag[rt][kt] = *(const bf16x8*)(ap + kt * 32);
    }

    f32x4 acc[2][8];
    #pragma unroll
    for (int rt = 0; rt < 2; rt++)
        #pragma unroll
        for (int nt = 0; nt < 8; nt++) {
            f32x4 z = {0.f, 0.f, 0.f, 0.f};
            acc[rt][nt] = z;
        }

    const short* bp = Wt + lr * D + lq * 8;
    #pragma unroll
    for (int nt = 0; nt < 8; nt++) {
        #pragma unroll
        for (int kt = 0; kt < 4; kt++) {
            bf16x8 b = *(const bf16x8*)(bp + nt * 16 * D + kt * 32);
            acc[0][nt] = __builtin_amdgcn_mfma_f32_16x16x32_bf16(afrag[0][kt], b, acc[0][nt], 0, 0, 0);
            acc[1][nt] = __builtin_amdgcn_mfma_f32_16x16x32_bf16(afrag[1][kt], b, acc[1][nt], 0, 0, 0);
        }
    }

    // C/D layout: col = lane&15, row = (lane>>4)*4 + reg
    float bcol[8];
    #pragma unroll
    for (int nt = 0; nt < 8; nt++) bcol[nt] = bias[nt * 16 + lr];

    #pragma unroll
    for (int rt = 0; rt < 2; rt++) {
        int row0 = m_base + rt * 16 + lq * 4;
        #pragma unroll
        for (int i2 = 0; i2 < 4; i2++) {
            int r = row0 + i2;
            if (r < N) {
                if (mode == 0) {
                    float dr = dinv[r];
                    #pragma unroll
                    for (int nt = 0; nt < 8; nt++) {
                        int col = nt * 16 + lr;
                        float val = fmaxf(acc[rt][nt][i2] + bcol[nt], 0.0f);
                        hb_out[(size_t)r * D + col] = f2bf(val * dr);
                    }
                } else {
                    #pragma unroll
                    for (int nt = 0; nt < 8; nt++) {
                        int col = nt * 16 + lr;
                        hrelu[(size_t)r * D + col] = fmaxf(acc[rt][nt][i2] + bcol[nt], 0.0f);
                    }
                }
            }
        }
    }
}

// ---- segmented pooling: batch is sorted, so graph g owns rows [gstart, gstart+cnt) ----
__global__ __launch_bounds__(256) void k_pool(const float* __restrict__ hrelu,
                                              const int* __restrict__ gstart,
                                              const int* __restrict__ gcnt,
                                              float* __restrict__ gmax,
                                              float* __restrict__ gsum) {
    int g = blockIdx.x;
    int c = threadIdx.x & 127;
    int p = threadIdx.x >> 7;          // 2 row-parities x 128 cols
    int start = gstart[g];
    int endr = start + gcnt[g];

    float mx0 = 0.f, mx1 = 0.f, sm0 = 0.f, sm1 = 0.f;
    int r = start + p;
    for (; r + 2 < endr; r += 4) {
        float v0 = hrelu[(size_t)r * D + c];
        float v1 = hrelu[(size_t)(r + 2) * D + c];
        mx0 = fmaxf(mx0, v0); sm0 += v0;
        mx1 = fmaxf(mx1, v1); sm1 += v1;
    }
    if (r < endr) {
        float v0 = hrelu[(size_t)r * D + c];
        mx0 = fmaxf(mx0, v0); sm0 += v0;
    }
    float mx = fmaxf(mx0, mx1), sm = sm0 + sm1;

    __shared__ float smx[128], ssm[128];
    if (p == 1) { smx[c] = mx; ssm[c] = sm; }
    __syncthreads();
    if (p == 0) {
        gmax[g * D + c] = fmaxf(mx, smx[c]);
        gsum[g * D + c] = sm + ssm[c];
    }
}

// ---- final: out[g] = [gmax, gsum/cnt, gsum] @ out_w + out_b ----
__global__ void k_final(const float* __restrict__ gmax, const float* __restrict__ gsum,
                        const int* __restrict__ gcnt, const float* __restrict__ ow,
                        const float* __restrict__ ob, float* __restrict__ out) {
    int g = blockIdx.x;
    int t = threadIdx.x;  // 64
    float part[10];
    #pragma unroll
    for (int o = 0; o < 10; o++) part[o] = 0.f;
    float invc = 1.0f / fmaxf((float)gcnt[g], 1.0f);
    for (int k = t; k < 3 * D; k += 64) {
        float pk;
        if (k < D) pk = gmax[g * D + k];
        else if (k < 2 * D) pk = gsum[g * D + (k - D)] * invc;
        else pk = gsum[g * D + (k - 2 * D)];
        const float* w = ow + k * 10;
        #pragma unroll
        for (int o = 0; o < 10; o++) part[o] += pk * w[o];
    }
    #pragma unroll
    for (int off = 32; off > 0; off >>= 1)
        #pragma unroll
        for (int o = 0; o < 10; o++) part[o] += __shfl_down(part[o], off, 64);
    if (t == 0)
        #pragma unroll
        for (int o = 0; o < 10; o++) out[g * 10 + o] = part[o] + ob[o];
}

extern "C" void kernel_launch(void* const* d_in, const int* in_sizes, int n_in,
                              void* d_out, int out_size, void* d_ws, size_t ws_size,
                              hipStream_t stream) {
    const float* x     = (const float*)d_in[0];
    const int*   ei    = (const int*)d_in[1];
    const int*   batch = (const int*)d_in[2];
    const float* convw = (const float*)d_in[3];
    const float* convb = (const float*)d_in[4];
    const float* outw  = (const float*)d_in[5];
    const float* outb  = (const float*)d_in[6];
    float* out = (float*)d_out;

    const int N = in_sizes[0] / D;        // 100000
    const int E = in_sizes[1] / 2;        // 1600000
    const int L = in_sizes[3] / (D * D);  // 3
    const int B = out_size / 10;          // 256

    const int* src = ei;
    const int* dst = ei + E;

    const int dpb   = (N + KB - 1) / KB;       // dst per coarse bucket (196)
    const int kpb   = dpb * NP;                // fine keys per bucket (1568)
    const int nkeys = KB * kpb;                // global fine-key space (802816)
    const int spp   = (N + NP - 1) / NP;       // src per pass-range

    char* p = (char*)d_ws;
    auto alloc = [&](size_t bytes) { char* r = p; p += (bytes + 255) & ~255ull; return r; };
    short* hb      = (short*)alloc((size_t)N * D * 2);      // bf16 pre-scaled feature rows
    short* gbuf    = (short*)alloc((size_t)N * D * 2);      // bf16 aggregated rows (GEMM input)
    float* hrelu   = (float*)alloc((size_t)N * D * 4);      // fp32 last-layer relu; ALIASED as staging
    short* Wt      = (short*)alloc((size_t)L * D * D * 2);  // bf16 W^T
    int*   row_ptr = (int*)alloc(((size_t)nkeys + 1) * 4);
    int*   csr_src = (int*)alloc((size_t)E * 4);
    int*   bcnt    = (int*)alloc((size_t)KB * 4);
    int*   bbase   = (int*)alloc((size_t)KB * 4);
    float* dinv    = (float*)alloc((size_t)N * 4);
    float* gmax    = (float*)alloc((size_t)B * D * 4);
    float* gsum    = (float*)alloc((size_t)B * D * 4);
    int*   gcnt    = (int*)alloc((size_t)B * 4);
    int*   gstart  = (int*)alloc(((size_t)B + 1) * 4);

    int* staging = (int*)hrelu;   // 512*8192*4 = 16.8 MB <= 51.2 MB; hrelu written only after k_build

    hipMemsetAsync(bcnt, 0, (size_t)KB * 4, stream);

    k_bucket<<<(E + 255) / 256, 256, 0, stream>>>(src, dst, bcnt, staging, E, dpb, spp);
    k_gseg<<<1, 512, 0, stream>>>(batch, gstart, N, B);
    k_gcnt_seg<<<1, 256, 0, stream>>>(gstart, gcnt, B);
    k_bscan<<<1, KB, 0, stream>>>(bcnt, bbase, row_ptr, E, nkeys);
    k_build<<<KB, 256, 0, stream>>>(staging, bcnt, bbase, row_ptr, csr_src, dinv, N, dpb);
    k_cvt_x<<<((N * D / 4) + 255) / 256, 256, 0, stream>>>(x, dinv, hb, N * D / 4);
    k_cvt_w<<<((L * D * D) + 255) / 256, 256, 0, stream>>>(convw, Wt, L * D * D);

    const int ablocks = (N + 15) / 16;
    const int gblocks = (N + 127) / 128;
    for (int l = 0; l < L; l++) {
        k_aggregate<<<ablocks, 256, 0, stream>>>(hb, row_ptr, csr_src, dinv, gbuf, N);
        k_gemm<<<gblocks, 256, 0, stream>>>(gbuf, Wt + l * D * D, convb + (size_t)l * D,
                                            dinv, hb, hrelu, N, (l == L - 1) ? 1 : 0);
    }
    k_pool<<<B, 256, 0, stream>>>(hrelu, gstart, gcnt, gmax, gsum);
    k_final<<<B, 64, 0, stream>>>(gmax, gsum, gcnt, outw, outb, out);
}

// Round 7
// 502.042 us; speedup vs baseline: 1.8301x; 1.8301x over previous
//
#include <hip/hip_runtime.h>
#include <hip/hip_bf16.h>

#define D 128
#define NP 8            // src-range sub-buckets per dst (aggregate pass loop)
#define DPB 256         // dst per coarse bucket (power of 2: b = d>>8)
#define KPB (DPB * NP)  // fine keys per bucket = 2048
#define SUB 64          // sub-cursors per bucket (contention killer)
#define CAP_SUB 128     // staging capacity per (sub, bucket); mean ~64, 8-sigma safe

typedef __attribute__((ext_vector_type(8))) __bf16 bf16x8;
typedef __attribute__((ext_vector_type(4))) float f32x4;
typedef __attribute__((ext_vector_type(4))) short s16x4;
typedef __attribute__((ext_vector_type(8))) short s16x8;

static __device__ __forceinline__ short f2bf(float f) {
    union { float f; unsigned u; } in; in.f = f;
    unsigned u = in.u;
    u += 0x7fffu + ((u >> 16) & 1u);   // round-to-nearest-even
    return (short)(u >> 16);
}

// ---- phase 1: coarse-bucket edges; 64 sub-cursors/bucket to kill contention ----
// pack: fineKey(11b: (d&255)*8 + (src>>14)) << 17 | src(17b)   [N < 2^17]
__global__ void k_bucket(const int* __restrict__ src, const int* __restrict__ dst,
                         int* __restrict__ bcnt, int* __restrict__ staging,
                         int E, int KBE) {
    int i = blockIdx.x * 256 + threadIdx.x;
    if (i >= E) return;
    int d = dst[i], s = src[i];
    int b = d >> 8;
    int key = ((d & 255) * NP) | (s >> 14);
    int j = blockIdx.x & (SUB - 1);      // j%8 == heuristic XCD -> j-stripe stays home
    int slot = atomicAdd(&bcnt[j * KBE + b], 1);
    if (slot < CAP_SUB) staging[((size_t)j * KBE + b) * CAP_SUB + slot] = (key << 17) | s;
}

// ---- exclusive scan of per-bucket totals (sum of capped sub-counts) ----
__global__ void k_bscan(const int* __restrict__ bcnt, int* __restrict__ bbase,
                        int* __restrict__ row_ptr, int nkeys, int KBE) {
    __shared__ int sm[512];
    int t = threadIdx.x;
    int v = 0;
    if (t < KBE) {
        for (int j = 0; j < SUB; j++) {
            int c = bcnt[j * KBE + t];
            v += (c > CAP_SUB) ? CAP_SUB : c;
        }
    }
    sm[t] = v;
    __syncthreads();
    for (int off = 1; off < 512; off <<= 1) {
        int x = (t >= off) ? sm[t - off] : 0;
        __syncthreads();
        sm[t] += x;
        __syncthreads();
    }
    if (t < KBE) bbase[t] = sm[t] - v;
    if (t == 511) row_ptr[nkeys] = sm[511];   // total staged edges (== E unless cap hit)
}

// ---- phase 2: per-bucket fine CSR build, all in LDS (no global atomics) ----
__global__ __launch_bounds__(256) void k_build(
    const int* __restrict__ staging, const int* __restrict__ bcnt,
    const int* __restrict__ bbase, int* __restrict__ row_ptr,
    int* __restrict__ csr_src, float* __restrict__ dinv, int N, int KBE)
{
    const int b = blockIdx.x;
    const int tid = threadIdx.x;
    __shared__ int cnt[KPB];
    __shared__ int subn[SUB];
    __shared__ int suboff[SUB + 1];
    __shared__ int chunkbuf[256];
    __shared__ int carry;

    if (tid < SUB) {
        int c = bcnt[tid * KBE + b];
        subn[tid] = (c > CAP_SUB) ? CAP_SUB : c;
    }
    for (int k = tid; k < KPB; k += 256) cnt[k] = 0;
    if (tid == 0) carry = 0;
    __syncthreads();
    if (tid == 0) {
        int a = 0;
        for (int j = 0; j < SUB; j++) { suboff[j] = a; a += subn[j]; }
        suboff[SUB] = a;
    }
    __syncthreads();
    const int nb = suboff[SUB];
    const int base = bbase[b];
    const int* __restrict__ stg = staging;

    // histogram over fine keys (flattened across the 64 sub-regions)
    for (int t = tid; t < nb; t += 256) {
        int lo = 0, hi = SUB;                      // find j: suboff[j] <= t < suboff[j+1]
        while (lo + 1 < hi) { int mid = (lo + hi) >> 1; if (suboff[mid] <= t) lo = mid; else hi = mid; }
        int w = stg[((size_t)lo * KBE + b) * CAP_SUB + (t - suboff[lo])];
        atomicAdd(&cnt[w >> 17], 1);
    }
    __syncthreads();

    // in-place exclusive scan of cnt[0..KPB)
    #pragma unroll 1
    for (int c = 0; c < KPB / 256; c++) {
        int idx = c * 256 + tid;
        int v = cnt[idx];
        chunkbuf[tid] = v;
        __syncthreads();
        for (int off = 1; off < 256; off <<= 1) {
            int x = (tid >= off) ? chunkbuf[tid - off] : 0;
            __syncthreads();
            chunkbuf[tid] += x;
            __syncthreads();
        }
        int excl = chunkbuf[tid] - v + carry;   // reads old carry
        cnt[idx] = excl;
        __syncthreads();
        if (tid == 255) carry += chunkbuf[255];
        __syncthreads();
    }

    // row_ptr (coalesced, contiguous global keys) + dinv for this dst range
    for (int k = tid; k < KPB; k += 256)
        row_ptr[(size_t)b * KPB + k] = base + cnt[k];
    for (int dl = tid; dl < DPB; dl += 256) {
        int d = b * DPB + dl;
        if (d < N) {
            int hi2 = (dl == DPB - 1) ? nb : cnt[(dl + 1) * NP];
            int deg = hi2 - cnt[dl * NP];
            dinv[d] = rsqrtf((float)deg + 1.0f);
        }
    }
    __syncthreads();

    // scatter into this bucket's contiguous csr region (LDS cursors)
    for (int t = tid; t < nb; t += 256) {
        int lo = 0, hi = SUB;
        while (lo + 1 < hi) { int mid = (lo + hi) >> 1; if (suboff[mid] <= t) lo = mid; else hi = mid; }
        int w = stg[((size_t)lo * KBE + b) * CAP_SUB + (t - suboff[lo])];
        int slot = base + atomicAdd(&cnt[w >> 17], 1);
        csr_src[slot] = w & 0x1FFFF;
    }
}

// ---- batch is SORTED: graph segment boundaries via binary search (no atomics) ----
__global__ void k_gseg(const int* __restrict__ batch, int* __restrict__ gstart,
                       int N, int B) {
    int g = blockIdx.x * blockDim.x + threadIdx.x;
    if (g > B) return;
    int lo = 0, hi = N;
    while (lo < hi) {                    // lower_bound: first i with batch[i] >= g
        int mid = (lo + hi) >> 1;
        if (batch[mid] < g) lo = mid + 1; else hi = mid;
    }
    gstart[g] = lo;
}

__global__ void k_gcnt_seg(const int* __restrict__ gstart, int* __restrict__ gcnt, int B) {
    int g = blockIdx.x * blockDim.x + threadIdx.x;
    if (g < B) gcnt[g] = gstart[g + 1] - gstart[g];
}

// ---- x' = dinv[i] * x  -> bf16 (pre-scaled feature rows) ----
__global__ void k_cvt_x(const float* __restrict__ x, const float* __restrict__ dinv,
                        short* __restrict__ xb, int total4) {
    int i = blockIdx.x * blockDim.x + threadIdx.x;
    if (i < total4) {
        float d = dinv[i >> 5];              // D/4 = 32 float4 per row
        float4 v = ((const float4*)x)[i];
        s16x4 o;
        o.x = f2bf(v.x * d); o.y = f2bf(v.y * d);
        o.z = f2bf(v.z * d); o.w = f2bf(v.w * d);
        ((s16x4*)xb)[i] = o;
    }
}

// ---- conv_w: fp32 [L][k][n] -> bf16 transposed [L][n][k] ----
__global__ void k_cvt_w(const float* __restrict__ W, short* __restrict__ Wt, int total) {
    int i = blockIdx.x * blockDim.x + threadIdx.x;
    if (i < total) {
        int l = i >> 14;
        int rem = i & 16383;
        int n = rem >> 7;
        int k = rem & 127;
        Wt[i] = f2bf(W[(l << 14) + (k << 7) + n]);
    }
}

// ---- pull-aggregation, src-range pass loop for L2 locality ----
// One 16-lane group owns one node (full 128-col row, 8 bf16/lane).
// Pass p gathers only rows in src-range p (4 MB slice -> XCD-L2 resident).
__global__ __launch_bounds__(256) void k_aggregate(
    const short* __restrict__ hb, const int* __restrict__ row_ptr,
    const int* __restrict__ csr_src, const float* __restrict__ dinv,
    short* __restrict__ g, int N)
{
    const int wave = threadIdx.x >> 6;
    const int lane = threadIdx.x & 63;
    const int group = lane >> 4;
    const int off = (lane & 15) * 8;
    const int i = blockIdx.x * 16 + wave * 4 + group;
    if (i >= N) return;   // no barriers below: early-out is safe

    float acc[8];
    {   // self-loop term
        bf16x8 v = *(const bf16x8*)(hb + (size_t)i * D + off);
        #pragma unroll
        for (int k = 0; k < 8; k++) acc[k] = (float)v[k];
    }

    const int kb = i * NP;
    int s = row_ptr[kb];
    #pragma unroll 1
    for (int p = 0; p < NP; p++) {
        int e = row_ptr[kb + p + 1];
        for (int t = s; t < e; t += 4) {   // 4-deep chained loads
            int i0 = csr_src[t];
            int i1 = (t + 1 < e) ? csr_src[t + 1] : -1;
            int i2 = (t + 2 < e) ? csr_src[t + 2] : -1;
            int i3 = (t + 3 < e) ? csr_src[t + 3] : -1;
            bf16x8 v0 = *(const bf16x8*)(hb + (size_t)i0 * D + off);
            bf16x8 v1, v2, v3;
            if (i1 >= 0) v1 = *(const bf16x8*)(hb + (size_t)i1 * D + off);
            if (i2 >= 0) v2 = *(const bf16x8*)(hb + (size_t)i2 * D + off);
            if (i3 >= 0) v3 = *(const bf16x8*)(hb + (size_t)i3 * D + off);
            #pragma unroll
            for (int k = 0; k < 8; k++) acc[k] += (float)v0[k];
            if (i1 >= 0) {
                #pragma unroll
                for (int k = 0; k < 8; k++) acc[k] += (float)v1[k];
            }
            if (i2 >= 0) {
                #pragma unroll
                for (int k = 0; k < 8; k++) acc[k] += (float)v2[k];
            }
            if (i3 >= 0) {
                #pragma unroll
                for (int k = 0; k < 8; k++) acc[k] += (float)v3[k];
            }
        }
        s = e;
    }

    const float di = dinv[i];
    s16x8 o;
    #pragma unroll
    for (int k = 0; k < 8; k++) o[k] = f2bf(acc[k] * di);
    *(s16x8*)(g + (size_t)i * D + off) = o;
}

// ---- bf16 MFMA GEMM: C = A[N x 128] * W, fused epilogue.
// mode 0: hb_out[r] = bf16( relu(C + b) * dinv[r] )   (pre-scaled next-layer rows)
// mode 1: hrelu[r]  = fp32 relu(C + b)                (pooling input)
__global__ __launch_bounds__(256) void k_gemm(const short* __restrict__ A,
                                              const short* __restrict__ Wt,
                                              const float* __restrict__ bias,
                                              const float* __restrict__ dinv,
                                              short* __restrict__ hb_out,
                                              float* __restrict__ hrelu,
                                              int N, int mode) {
    const int wave = threadIdx.x >> 6;
    const int lane = threadIdx.x & 63;
    const int m_base = blockIdx.x * 128 + wave * 32;
    const int lr = lane & 15;
    const int lq = lane >> 4;

    bf16x8 afrag[2][4];
    #pragma unroll
    for (int rt = 0; rt < 2; rt++) {
        int m = m_base + rt * 16 + lr;
        if (m >= N) m = N - 1;
        const short* ap = A + (size_t)m * D + lq * 8;
        #pragma unroll
        for (int kt = 0; kt < 4; kt++)
            afrag[rt][kt] = *(const bf16x8*)(ap + kt * 32);
    }

    f32x4 acc[2][8];
    #pragma unroll
    for (int rt = 0; rt < 2; rt++)
        #pragma unroll
        for (int nt = 0; nt < 8; nt++) {
            f32x4 z = {0.f, 0.f, 0.f, 0.f};
            acc[rt][nt] = z;
        }

    const short* bp = Wt + lr * D + lq * 8;
    #pragma unroll
    for (int nt = 0; nt < 8; nt++) {
        #pragma unroll
        for (int kt = 0; kt < 4; kt++) {
            bf16x8 b = *(const bf16x8*)(bp + nt * 16 * D + kt * 32);
            acc[0][nt] = __builtin_amdgcn_mfma_f32_16x16x32_bf16(afrag[0][kt], b, acc[0][nt], 0, 0, 0);
            acc[1][nt] = __builtin_amdgcn_mfma_f32_16x16x32_bf16(afrag[1][kt], b, acc[1][nt], 0, 0, 0);
        }
    }

    // C/D layout: col = lane&15, row = (lane>>4)*4 + reg
    float bcol[8];
    #pragma unroll
    for (int nt = 0; nt < 8; nt++) bcol[nt] = bias[nt * 16 + lr];

    #pragma unroll
    for (int rt = 0; rt < 2; rt++) {
        int row0 = m_base + rt * 16 + lq * 4;
        #pragma unroll
        for (int i2 = 0; i2 < 4; i2++) {
            int r = row0 + i2;
            if (r < N) {
                if (mode == 0) {
                    float dr = dinv[r];
                    #pragma unroll
                    for (int nt = 0; nt < 8; nt++) {
                        int col = nt * 16 + lr;
                        float val = fmaxf(acc[rt][nt][i2] + bcol[nt], 0.0f);
                        hb_out[(size_t)r * D + col] = f2bf(val * dr);
                    }
                } else {
                    #pragma unroll
                    for (int nt = 0; nt < 8; nt++) {
                        int col = nt * 16 + lr;
                        hrelu[(size_t)r * D + col] = fmaxf(acc[rt][nt][i2] + bcol[nt], 0.0f);
                    }
                }
            }
        }
    }
}

// ---- segmented pooling: batch is sorted, so graph g owns rows [gstart, gstart+cnt) ----
__global__ __launch_bounds__(256) void k_pool(const float* __restrict__ hrelu,
                                              const int* __restrict__ gstart,
                                              const int* __restrict__ gcnt,
                                              float* __restrict__ gmax,
                                              float* __restrict__ gsum) {
    int g = blockIdx.x;
    int c = threadIdx.x & 127;
    int p = threadIdx.x >> 7;          // 2 row-parities x 128 cols
    int start = gstart[g];
    int endr = start + gcnt[g];

    float mx0 = 0.f, mx1 = 0.f, sm0 = 0.f, sm1 = 0.f;
    int r = start + p;
    for (; r + 2 < endr; r += 4) {
        float v0 = hrelu[(size_t)r * D + c];
        float v1 = hrelu[(size_t)(r + 2) * D + c];
        mx0 = fmaxf(mx0, v0); sm0 += v0;
        mx1 = fmaxf(mx1, v1); sm1 += v1;
    }
    if (r < endr) {
        float v0 = hrelu[(size_t)r * D + c];
        mx0 = fmaxf(mx0, v0); sm0 += v0;
    }
    float mx = fmaxf(mx0, mx1), sm = sm0 + sm1;

    __shared__ float smx[128], ssm[128];
    if (p == 1) { smx[c] = mx; ssm[c] = sm; }
    __syncthreads();
    if (p == 0) {
        gmax[g * D + c] = fmaxf(mx, smx[c]);
        gsum[g * D + c] = sm + ssm[c];
    }
}

// ---- final: out[g] = [gmax, gsum/cnt, gsum] @ out_w + out_b ----
__global__ void k_final(const float* __restrict__ gmax, const float* __restrict__ gsum,
                        const int* __restrict__ gcnt, const float* __restrict__ ow,
                        const float* __restrict__ ob, float* __restrict__ out) {
    int g = blockIdx.x;
    int t = threadIdx.x;  // 64
    float part[10];
    #pragma unroll
    for (int o = 0; o < 10; o++) part[o] = 0.f;
    float invc = 1.0f / fmaxf((float)gcnt[g], 1.0f);
    for (int k = t; k < 3 * D; k += 64) {
        float pk;
        if (k < D) pk = gmax[g * D + k];
        else if (k < 2 * D) pk = gsum[g * D + (k - D)] * invc;
        else pk = gsum[g * D + (k - 2 * D)];
        const float* w = ow + k * 10;
        #pragma unroll
        for (int o = 0; o < 10; o++) part[o] += pk * w[o];
    }
    #pragma unroll
    for (int off = 32; off > 0; off >>= 1)
        #pragma unroll
        for (int o = 0; o < 10; o++) part[o] += __shfl_down(part[o], off, 64);
    if (t == 0)
        #pragma unroll
        for (int o = 0; o < 10; o++) out[g * 10 + o] = part[o] + ob[o];
}

extern "C" void kernel_launch(void* const* d_in, const int* in_sizes, int n_in,
                              void* d_out, int out_size, void* d_ws, size_t ws_size,
                              hipStream_t stream) {
    const float* x     = (const float*)d_in[0];
    const int*   ei    = (const int*)d_in[1];
    const int*   batch = (const int*)d_in[2];
    const float* convw = (const float*)d_in[3];
    const float* convb = (const float*)d_in[4];
    const float* outw  = (const float*)d_in[5];
    const float* outb  = (const float*)d_in[6];
    float* out = (float*)d_out;

    const int N = in_sizes[0] / D;        // 100000
    const int E = in_sizes[1] / 2;        // 1600000
    const int L = in_sizes[3] / (D * D);  // 3
    const int B = out_size / 10;          // 256

    const int* src = ei;
    const int* dst = ei + E;

    const int KBE   = (N + DPB - 1) / DPB;     // coarse buckets (391)
    const int nkeys = KBE * KPB;               // global fine-key space

    char* p = (char*)d_ws;
    auto alloc = [&](size_t bytes) { char* r = p; p += (bytes + 255) & ~255ull; return r; };
    short* hb      = (short*)alloc((size_t)N * D * 2);      // bf16 pre-scaled feature rows
    short* gbuf    = (short*)alloc((size_t)N * D * 2);      // bf16 aggregated rows (GEMM input)
    float* hrelu   = (float*)alloc((size_t)N * D * 4);      // fp32 last-layer relu; ALIASED as staging
    short* Wt      = (short*)alloc((size_t)L * D * D * 2);  // bf16 W^T
    int*   row_ptr = (int*)alloc(((size_t)nkeys + 1) * 4);
    int*   csr_src = (int*)alloc((size_t)E * 4);
    int*   bcnt    = (int*)alloc((size_t)SUB * KBE * 4);
    int*   bbase   = (int*)alloc((size_t)KBE * 4);
    float* dinv    = (float*)alloc((size_t)N * 4);
    float* gmax    = (float*)alloc((size_t)B * D * 4);
    float* gsum    = (float*)alloc((size_t)B * D * 4);
    int*   gcnt    = (int*)alloc((size_t)B * 4);
    int*   gstart  = (int*)alloc(((size_t)B + 1) * 4);

    // staging: SUB*KBE*CAP_SUB*4 = 64*391*128*4 = 12.8 MB  <= hrelu's 51.2 MB
    int* staging = (int*)hrelu;   // hrelu written only after k_build completes

    hipMemsetAsync(bcnt, 0, (size_t)SUB * KBE * 4, stream);

    k_bucket<<<(E + 255) / 256, 256, 0, stream>>>(src, dst, bcnt, staging, E, KBE);
    k_gseg<<<1, 512, 0, stream>>>(batch, gstart, N, B);
    k_gcnt_seg<<<1, 256, 0, stream>>>(gstart, gcnt, B);
    k_bscan<<<1, 512, 0, stream>>>(bcnt, bbase, row_ptr, nkeys, KBE);
    k_build<<<KBE, 256, 0, stream>>>(staging, bcnt, bbase, row_ptr, csr_src, dinv, N, KBE);
    k_cvt_x<<<((N * D / 4) + 255) / 256, 256, 0, stream>>>(x, dinv, hb, N * D / 4);
    k_cvt_w<<<((L * D * D) + 255) / 256, 256, 0, stream>>>(convw, Wt, L * D * D);

    const int ablocks = (N + 15) / 16;
    const int gblocks = (N + 127) / 128;
    for (int l = 0; l < L; l++) {
        k_aggregate<<<ablocks, 256, 0, stream>>>(hb, row_ptr, csr_src, dinv, gbuf, N);
        k_gemm<<<gblocks, 256, 0, stream>>>(gbuf, Wt + l * D * D, convb + (size_t)l * D,
                                            dinv, hb, hrelu, N, (l == L - 1) ? 1 : 0);
    }
    k_pool<<<B, 256, 0, stream>>>(hrelu, gstart, gcnt, gmax, gsum);
    k_final<<<B, 64, 0, stream>>>(gmax, gsum, gcnt, outw, outb, out);
}